// Round 3
// baseline (80.740 us; speedup 1.0000x reference)
//
#include <hip/hip_runtime.h>

// ParabolicPool2D: out[b,c,i,j] = max_{p,q} f[b,c,2i+p,2j+q] - z[p,q]*t[c]
// z = [[1,.5,1],[.5,0,.5],[1,.5,1]]  -> corners: -t, edges: -0.5t, center: 0
// B=16, C=256, H=W=128, ks=3, stride=2 -> oH=oW=63
//
// v3: register-rolling row reuse. Thread (bc, s, k) computes output rows
// 9s..9s+8 for columns j=4k..4k+3 (k=15: 3 cols). Per output row it loads
// only the 2 new input rows (2 x float4 + tail); the third is rolled from
// the previous iteration. Eliminates the cross-XCD row re-fetch of v1.

#define C_DIM 256
#define H_DIM 128
#define W_DIM 128
#define OH 63
#define OW 63
#define SEGS 7
#define RPS 9   // output rows per segment/thread

__global__ __launch_bounds__(256) void parab_pool_v3(
    const float* __restrict__ f,
    const float* __restrict__ t,
    float* __restrict__ out)
{
    int tid  = blockIdx.x * blockDim.x + threadIdx.x;
    int k    = tid & 15;          // column band: j = 4k..4k+3
    int rest = tid >> 4;          // bc*SEGS + s
    int s    = rest % SEGS;
    int bc   = rest / SEGS;
    int c    = bc & (C_DIM - 1);

    const float a  = -t[c];       // corner offset
    const float ha = 0.5f * a;    // edge offset
    const bool full = (k != 15);
    const int  tail = full ? 8 : 0;   // clamp tail load in-bounds for k=15

    const float* base = f + ((size_t)(bc * H_DIM + 18 * s)) * W_DIM + 8 * k;
    float* ob = out + ((size_t)(bc * OH + RPS * s)) * OW + 4 * k;

    float top[9], mid[9], bot[9];

#define LOAD_ROW(dst, P) do { \
    const float* _p = (P); \
    float4 _A = *(const float4*)(_p); \
    float4 _B = *(const float4*)(_p + 4); \
    dst[0]=_A.x; dst[1]=_A.y; dst[2]=_A.z; dst[3]=_A.w; \
    dst[4]=_B.x; dst[5]=_B.y; dst[6]=_B.z; dst[7]=_B.w; \
    dst[8]=_p[tail]; } while (0)

    LOAD_ROW(top, base);

    #pragma unroll
    for (int it = 0; it < RPS; ++it) {
        LOAD_ROW(mid, base + (2 * it + 1) * W_DIM);
        LOAD_ROW(bot, base + (2 * it + 2) * W_DIM);

        float res[4];
        #pragma unroll
        for (int l = 0; l < 4; ++l) {
            const int c0 = 2 * l, c1 = 2 * l + 1, c2 = 2 * l + 2;
            float corners = fmaxf(fmaxf(top[c0], top[c2]), fmaxf(bot[c0], bot[c2]));
            float edges   = fmaxf(fmaxf(top[c1], bot[c1]), fmaxf(mid[c0], mid[c2]));
            res[l] = fmaxf(mid[c1], fmaxf(corners + a, edges + ha));
        }

        float* o = ob + it * OW;
        __builtin_nontemporal_store(res[0], o + 0);
        __builtin_nontemporal_store(res[1], o + 1);
        __builtin_nontemporal_store(res[2], o + 2);
        if (full) __builtin_nontemporal_store(res[3], o + 3);

        #pragma unroll
        for (int x = 0; x < 9; ++x) top[x] = bot[x];
    }
#undef LOAD_ROW
}

extern "C" void kernel_launch(void* const* d_in, const int* in_sizes, int n_in,
                              void* d_out, int out_size, void* d_ws, size_t ws_size,
                              hipStream_t stream)
{
    const float* f = (const float*)d_in[0];
    const float* t = (const float*)d_in[1];
    float* out = (float*)d_out;

    int total_threads = 16 * C_DIM * SEGS * 16;   // 458752
    int block = 256;
    int grid = total_threads / block;             // 1792, exact

    parab_pool_v3<<<grid, block, 0, stream>>>(f, t, out);
}

// Round 4
// 58.781 us; speedup vs baseline: 1.3736x; 1.3736x over previous
//
#include <hip/hip_runtime.h>

// ParabolicPool2D: out[b,c,i,j] = max_{p,q} f[b,c,2i+p,2j+q] - z[p,q]*t[c]
// z = [[1,.5,1],[.5,0,.5],[1,.5,1]]  -> corners: -t, edges: -0.5t, center: 0
// B=16, C=256, H=W=128, ks=3, stride=2 -> oH=oW=63
//
// v4: v1's massive-TLP scalar structure, but each thread computes TWO
// vertically adjacent outputs (i0, i0+1), sharing input row 2*i0+2.
// 15 independent scalar loads per thread (7.5/output vs v1's 9).
// Plain stores (v3 showed nontemporal stores double WRITE_SIZE).

#define C_DIM 256
#define H_DIM 128
#define W_DIM 128
#define OH 63
#define OW 63
#define PAIRS 32   // ceil(63/2): pair ip covers output rows 2ip, 2ip+1

__global__ __launch_bounds__(256) void parab_pool_v4(
    const float* __restrict__ f,
    const float* __restrict__ t,
    float* __restrict__ out)
{
    int idx = blockIdx.x * blockDim.x + threadIdx.x;

    int j   = idx % OW;
    int tmp = idx / OW;
    int ip  = tmp % PAIRS;
    int bc  = tmp / PAIRS;
    int c   = bc & (C_DIM - 1);

    const float a  = -t[c];       // corner offset
    const float ha = 0.5f * a;    // edge offset

    const int i0 = 2 * ip;
    const bool has2 = (i0 + 1 < OH);      // ip==31 -> only one output row

    const int r0 = 4 * ip;                 // input rows r0..r0+4
    const int r3 = has2 ? r0 + 3 : r0 + 1; // clamped in-bounds duplicates
    const int r4 = has2 ? r0 + 4 : r0 + 2;

    const float* img = f + (size_t)bc * (H_DIM * W_DIM) + 2 * j;

    const float* p0 = img + (size_t)r0 * W_DIM;
    const float* p1 = img + (size_t)(r0 + 1) * W_DIM;
    const float* p2 = img + (size_t)(r0 + 2) * W_DIM;
    const float* p3 = img + (size_t)r3 * W_DIM;
    const float* p4 = img + (size_t)r4 * W_DIM;

    // row 0
    float a0 = p0[0], a1 = p0[1], a2 = p0[2];
    // row 1
    float b0 = p1[0], b1 = p1[1], b2 = p1[2];
    // row 2 (shared)
    float c0 = p2[0], c1 = p2[1], c2 = p2[2];
    // row 3
    float d0 = p3[0], d1 = p3[1], d2 = p3[2];
    // row 4
    float e0 = p4[0], e1 = p4[1], e2 = p4[2];

    // output row i0: rows a,b,c
    float cor0 = fmaxf(fmaxf(a0, a2), fmaxf(c0, c2));
    float edg0 = fmaxf(fmaxf(a1, c1), fmaxf(b0, b2));
    float v0   = fmaxf(b1, fmaxf(cor0 + a, edg0 + ha));

    // output row i0+1: rows c,d,e
    float cor1 = fmaxf(fmaxf(c0, c2), fmaxf(e0, e2));
    float edg1 = fmaxf(fmaxf(c1, e1), fmaxf(d0, d2));
    float v1   = fmaxf(d1, fmaxf(cor1 + a, edg1 + ha));

    float* o = out + ((size_t)bc * OH + i0) * OW + j;
    o[0] = v0;
    if (has2) o[OW] = v1;
}

extern "C" void kernel_launch(void* const* d_in, const int* in_sizes, int n_in,
                              void* d_out, int out_size, void* d_ws, size_t ws_size,
                              hipStream_t stream)
{
    const float* f = (const float*)d_in[0];
    const float* t = (const float*)d_in[1];
    float* out = (float*)d_out;

    int total = 16 * C_DIM * PAIRS * OW;   // 8,257,536
    int block = 256;
    int grid = total / block;              // 32256, exact

    parab_pool_v4<<<grid, block, 0, stream>>>(f, t, out);
}